// Round 15
// baseline (864.449 us; speedup 1.0000x reference)
//
#include <hip/hip_runtime.h>
#include <hip/hip_bf16.h>
#include <math.h>

// Problem constants (from reference)
#define N_NODES_C 100000
#define E_ORIG    400000
#define E_TOT     500000   // + self loops
#define E_PAD     (E_TOT + 3 * N_NODES_C)   // CSR padded to multiple-of-4 per node
#define N_GRAPHS_C 2000
#define KDIM      256      // HEADS*HID = OUT

typedef __attribute__((ext_vector_type(8))) short short8v;  // 8 bf16 = 4 VGPR
typedef __attribute__((ext_vector_type(4))) float f32x4;

__device__ __forceinline__ void gload_lds16(const void* g, void* l) {
    __builtin_amdgcn_global_load_lds(
        (const __attribute__((address_space(1))) unsigned int*)g,
        (__attribute__((address_space(3))) unsigned int*)l, 16, 0, 0);
}

__device__ __forceinline__ float bflo(unsigned u) { return __uint_as_float(u << 16); }
__device__ __forceinline__ float bfhi(unsigned u) { return __uint_as_float(u & 0xffff0000u); }

// ---------------------------------------------------------------------------
// Conversions to bf16 + degree count, ONE kernel (regions by flat index).
// ---------------------------------------------------------------------------
#define XE  (N_NODES_C * 64)
#define W1E (256 * 64)
#define WBE (256 * 256)
__global__ __launch_bounds__(256) void conv_all_count(
        const float* __restrict__ x, const float* __restrict__ W1,
        const float* __restrict__ W2, const float* __restrict__ W3,
        const int* __restrict__ ei,
        __hip_bfloat16* __restrict__ Xb, __hip_bfloat16* __restrict__ Wt1,
        __hip_bfloat16* __restrict__ Wt2, __hip_bfloat16* __restrict__ Wt3,
        int* __restrict__ deg) {
    int idx = blockIdx.x * 256 + threadIdx.x;
    if (idx < E_TOT) {
        int d = (idx < E_ORIG) ? ei[E_ORIG + idx] : (idx - E_ORIG);
        atomicAdd(&deg[d], 1);
    }
    if (idx < XE) {
        int row = idx >> 6, c = idx & 63;
        float v = (c < 58) ? x[row * 58 + c] : 0.f;
        Xb[idx] = __float2bfloat16(v);
    } else if (idx < XE + W1E) {
        int i = idx - XE;
        int c = i >> 6, k = i & 63;               // KPAD=64, K=58
        float v = (k < 58) ? W1[k * 256 + c] : 0.f;
        Wt1[i] = __float2bfloat16(v);
    } else if (idx < XE + W1E + WBE) {
        int i = idx - XE - W1E;
        int c = i >> 8, k = i & 255;
        Wt2[i] = __float2bfloat16(W2[k * 256 + c]);
    } else if (idx < XE + W1E + 2 * WBE) {
        int i = idx - XE - W1E - WBE;
        int c = i >> 8, k = i & 255;
        Wt3[i] = __float2bfloat16(W3[k * 256 + c]);
    }
}

// ---------------------------------------------------------------------------
// CSR scan over PADDED degrees ((deg+3)&~3) + fix-up + scatter (+pad fill).
// ---------------------------------------------------------------------------
__global__ void scan_chunk(const int* __restrict__ in, int* __restrict__ out,
                           int* __restrict__ partials, int n) {
    __shared__ int s[256];
    int tid = threadIdx.x;
    int i = blockIdx.x * 256 + tid;
    int dv = (i < n) ? in[i] : 0;
    int v = (dv + 3) & ~3;                     // padded degree (0 stays 0)
    s[tid] = v;
    __syncthreads();
    for (int off = 1; off < 256; off <<= 1) {
        int t = (tid >= off) ? s[tid - off] : 0;
        __syncthreads();
        s[tid] += t;
        __syncthreads();
    }
    if (i < n) out[i] = s[tid] - v;            // exclusive within chunk
    if (tid == 255) partials[blockIdx.x] = s[255];
}

__global__ void scan_fix(int* __restrict__ rowoff, const int* __restrict__ partials, int n) {
    __shared__ int sred[256];
    int t = threadIdx.x;
    int acc = 0;
    for (int i = t; i < blockIdx.x; i += 256) acc += partials[i];
    sred[t] = acc;
    __syncthreads();
    for (int off = 128; off; off >>= 1) {
        if (t < off) sred[t] += sred[t + off];
        __syncthreads();
    }
    int base = sred[0];
    int i = blockIdx.x * 256 + t;
    if (i < n) rowoff[i] += base;
}

// scatter + pad fill fused: pads write disjoint slots [base+deg, base+paddeg)
__global__ void scatter_k(const int* __restrict__ ei, const int* __restrict__ rowoff,
                          int* cursor, int* __restrict__ csr_src,
                          int* __restrict__ csr_dst, const int* __restrict__ deg) {
    int e = blockIdx.x * 256 + threadIdx.x;
    if (e < E_TOT) {
        int s, d;
        if (e < E_ORIG) { s = ei[e]; d = ei[E_ORIG + e]; }
        else            { s = e - E_ORIG; d = s; }
        int pos = rowoff[d] + atomicAdd(&cursor[d], 1);
        csr_src[pos] = s;
        csr_dst[pos] = d;
    }
    if (e < N_NODES_C) {
        int dg = deg[e];
        int pd = (dg + 3) & ~3;
        int base = rowoff[e];
        for (int j = dg; j < pd; j++) {
            csr_src[base + j] = e | 0x80000000;
            csr_dst[base + j] = e;
        }
    }
}

// ---------------------------------------------------------------------------
// MFMA bf16 GEMM: H = X @ W + fused attention dots ES/ED.
// 128 rows x 256 cols tile, 8 waves (512 threads), wave tile 32x128,
// acc[2][8] = 64 AGPR; __launch_bounds__(512,4) caps 128 unified regs ->
// 4 waves/SIMD, 2 blocks/CU (50% occ) vs r14's 25% (acc[4][8] = 232 regs).
// Staging (swizzle + global_load_lds) identical to r14; 6 loads/wave/tile.
// ---------------------------------------------------------------------------
template <int KPAD, int NH>
__global__ __launch_bounds__(512, 4) void gemm_mfma(
        const __hip_bfloat16* __restrict__ Xb, const __hip_bfloat16* __restrict__ Wt,
        const float* __restrict__ ASRC, const float* __restrict__ ADST,
        __hip_bfloat16* __restrict__ H, float* __restrict__ ES, float* __restrict__ ED) {
    __shared__ char As[128 * 128];                   // [128 rows][64 k] bf16
    __shared__ char Bs[256 * 128];                   // [256 cols][64 k] bf16
    __shared__ float red[2][128][2];                 // NH==1 cross-wave ES/ED

    const int t = threadIdx.x;
    const int wv = t >> 6, lane = t & 63;
    const int wr = wv >> 1, wc = wv & 1;             // wr 0..3 (32 rows), wc 0..1
    const int r15 = lane & 15, hi = lane >> 4;
    const int n0 = blockIdx.x * 128;
    const int srow = lane >> 3;                      // staging: row-within-8
    const int sx = ((lane & 7) ^ srow) * 16;         // pre-swizzled source chunk
    constexpr int KB = KPAD * 2;                     // row bytes

    f32x4 acc[2][8];
#pragma unroll
    for (int m = 0; m < 2; m++)
#pragma unroll
        for (int n = 0; n < 8; n++) acc[m][n] = (f32x4){0.f, 0.f, 0.f, 0.f};

    for (int kt = 0; kt < KPAD / 64; kt++) {
        if (kt) __syncthreads();
        const int k0b = kt * 128;
#pragma unroll
        for (int p = 0; p < 2; p++) {                // A: 16 segs, 2/wave
            int i = wv * 2 + p;
            int gr = n0 + i * 8 + srow;
            if (gr > N_NODES_C - 1) gr = N_NODES_C - 1;
            gload_lds16((const char*)Xb + (size_t)gr * KB + k0b + sx, As + i * 1024);
        }
#pragma unroll
        for (int p = 0; p < 4; p++) {                // B: 32 segs, 4/wave
            int i = wv * 4 + p;
            int col = i * 8 + srow;
            gload_lds16((const char*)Wt + (size_t)col * KB + k0b + sx, Bs + i * 1024);
        }
        asm volatile("s_waitcnt vmcnt(0)" ::: "memory");
        __syncthreads();

#pragma unroll
        for (int ks = 0; ks < 2; ks++) {
            const int cx = ((ks * 4 + hi) ^ (r15 & 7)) * 16;  // swizzled chunk byte
            short8v a0 = *(const short8v*)(As + (wr * 32 + 0  + r15) * 128 + cx);
            short8v a1 = *(const short8v*)(As + (wr * 32 + 16 + r15) * 128 + cx);
#pragma unroll
            for (int n = 0; n < 8; n++) {
                short8v b = *(const short8v*)(Bs + (wc * 128 + n * 16 + r15) * 128 + cx);
                acc[0][n] = __builtin_amdgcn_mfma_f32_16x16x32_bf16(a0, b, acc[0][n], 0, 0, 0);
                acc[1][n] = __builtin_amdgcn_mfma_f32_16x16x32_bf16(a1, b, acc[1][n], 0, 0, 0);
            }
        }
    }

    // ---- epilogue: H (bf16) + attention dots ----
    float asv[8], adv[8];
#pragma unroll
    for (int n = 0; n < 8; n++) {
        int col = wc * 128 + n * 16 + r15;
        asv[n] = ASRC[col];
        adv[n] = ADST[col];
    }

#pragma unroll
    for (int m = 0; m < 2; m++) {
#pragma unroll
        for (int j = 0; j < 4; j++) {
            int lrow = wr * 32 + m * 16 + hi * 4 + j;
            int row = n0 + lrow;
            bool ok = row < N_NODES_C;
            if (ok) {
#pragma unroll
                for (int n = 0; n < 8; n++)
                    H[(size_t)row * KDIM + wc * 128 + n * 16 + r15] =
                        __float2bfloat16(acc[m][n][j]);
            }
            if (NH == 4) {
                float p0s = 0.f, p1s = 0.f, p0d = 0.f, p1d = 0.f;
#pragma unroll
                for (int n = 0; n < 4; n++) {
                    p0s = fmaf(acc[m][n][j], asv[n], p0s);
                    p0d = fmaf(acc[m][n][j], adv[n], p0d);
                    p1s = fmaf(acc[m][n + 4][j], asv[n + 4], p1s);
                    p1d = fmaf(acc[m][n + 4][j], adv[n + 4], p1d);
                }
#pragma unroll
                for (int s = 8; s; s >>= 1) {
                    p0s += __shfl_xor(p0s, s, 16);
                    p0d += __shfl_xor(p0d, s, 16);
                    p1s += __shfl_xor(p1s, s, 16);
                    p1d += __shfl_xor(p1d, s, 16);
                }
                if (r15 == 0 && ok) {
                    ES[row * 4 + wc * 2 + 0] = p0s;
                    ES[row * 4 + wc * 2 + 1] = p1s;
                    ED[row * 4 + wc * 2 + 0] = p0d;
                    ED[row * 4 + wc * 2 + 1] = p1d;
                }
            } else {
                float ps = 0.f, pd = 0.f;
#pragma unroll
                for (int n = 0; n < 8; n++) {
                    ps = fmaf(acc[m][n][j], asv[n], ps);
                    pd = fmaf(acc[m][n][j], adv[n], pd);
                }
#pragma unroll
                for (int s = 8; s; s >>= 1) {
                    ps += __shfl_xor(ps, s, 16);
                    pd += __shfl_xor(pd, s, 16);
                }
                if (r15 == 0) { red[0][lrow][wc] = ps; red[1][lrow][wc] = pd; }
            }
        }
    }
    if (NH == 1) {
        __syncthreads();
        if (t < 128) {
            int row = n0 + t;
            if (row < N_NODES_C) {
                ES[row] = red[0][t][0] + red[0][t][1];
                ED[row] = red[1][t][0] + red[1][t][1];
            }
        }
    }
}

// ---------------------------------------------------------------------------
// Fused per-dst softmax aggregation (r12 structure, wall-pinned). POOL=true
// (layer 3): skip Nb write; encoded-uint atomicMax straight into d_out
// (max is idempotent -> replay-safe; d_out memset(0) = below all encodings).
// ---------------------------------------------------------------------------
#define ECAP 160
template <int NH, bool RELU, bool POOL>
__global__ __launch_bounds__(256) void agg_kernel(
        const __hip_bfloat16* __restrict__ H, const int* __restrict__ rowoff,
        const int* __restrict__ csr_src, const int* __restrict__ csr_dst,
        const float* __restrict__ ES, const float* __restrict__ ED,
        const float* __restrict__ bias, __hip_bfloat16* __restrict__ Out,
        const int* __restrict__ batch, unsigned* __restrict__ outw) {
    __shared__ float Els[ECAP * NH];
    __shared__ int   Sls[ECAP];
    __shared__ int   roff[9];
    int t = threadIdx.x;
    int n0 = blockIdx.x * 8;                          // grid*8 == N exactly
    if (t < 9) roff[t] = rowoff[n0 + t];
    __syncthreads();
    int beg0 = roff[0];
    int ne = roff[8] - beg0;
    int nl = (ne < ECAP) ? ne : ECAP;
    for (int j = t; j < nl; j += 256) {
        int slot = beg0 + j;
        int srcj = csr_src[slot];
        bool padj = srcj < 0;
        srcj &= 0x7fffffff;
        int dj = csr_dst[slot];
        Sls[j] = srcj;
        if (NH == 4) {
            float4 es = *(const float4*)&ES[srcj * 4];
            float4 ed = *(const float4*)&ED[dj * 4];
            float e;
            e = es.x + ed.x; e = (e > 0.f) ? e : 0.2f * e; Els[j * 4 + 0] = padj ? -1e30f : e;
            e = es.y + ed.y; e = (e > 0.f) ? e : 0.2f * e; Els[j * 4 + 1] = padj ? -1e30f : e;
            e = es.z + ed.z; e = (e > 0.f) ? e : 0.2f * e; Els[j * 4 + 2] = padj ? -1e30f : e;
            e = es.w + ed.w; e = (e > 0.f) ? e : 0.2f * e; Els[j * 4 + 3] = padj ? -1e30f : e;
        } else {
            float e = ES[srcj] + ED[dj];
            e = (e > 0.f) ? e : 0.2f * e;
            Els[j] = padj ? -1e30f : e;
        }
    }
    __syncthreads();

    int g = t >> 5;
    int node = n0 + g;
    int l = t & 31;
    int c0 = l * 8;
    int head = (NH == 4) ? (l >> 3) : 0;
    int jb = roff[g] - beg0, je = roff[g + 1] - beg0;
    int jeF = (je < ECAP) ? je : ECAP;

    float m = -1e30f;
    for (int j = jb; j < jeF; j++) m = fmaxf(m, Els[j * NH + head]);
    if (je > ECAP) {                                  // never in practice
        float edv = ED[node * NH + head];
        for (int j = ECAP; j < je; j++) {
            int sj = csr_src[beg0 + j];
            if (sj < 0) continue;
            float e = ES[sj * NH + head] + edv;
            e = (e > 0.f) ? e : 0.2f * e;
            m = fmaxf(m, e);
        }
    }

    float s = 0.f;
    float a[8];
#pragma unroll
    for (int i = 0; i < 8; i++) a[i] = 0.f;
    const unsigned short* Hu = (const unsigned short*)H;

#define ACC8(v, p) \
    a[0] = fmaf(p, bflo(v.x), a[0]); a[1] = fmaf(p, bfhi(v.x), a[1]); \
    a[2] = fmaf(p, bflo(v.y), a[2]); a[3] = fmaf(p, bfhi(v.y), a[3]); \
    a[4] = fmaf(p, bflo(v.z), a[4]); a[5] = fmaf(p, bfhi(v.z), a[5]); \
    a[6] = fmaf(p, bflo(v.w), a[6]); a[7] = fmaf(p, bfhi(v.w), a[7]);

    int j = jb;
    for (; j + 4 <= jeF; j += 4) {                    // pure quads (padded CSR)
        int s0 = Sls[j], s1 = Sls[j + 1], s2 = Sls[j + 2], s3 = Sls[j + 3];
        float e0 = Els[(j + 0) * NH + head], e1 = Els[(j + 1) * NH + head];
        float e2 = Els[(j + 2) * NH + head], e3 = Els[(j + 3) * NH + head];
        uint4 v0 = *(const uint4*)(Hu + (size_t)s0 * KDIM + c0);
        uint4 v1 = *(const uint4*)(Hu + (size_t)s1 * KDIM + c0);
        uint4 v2 = *(const uint4*)(Hu + (size_t)s2 * KDIM + c0);
        uint4 v3 = *(const uint4*)(Hu + (size_t)s3 * KDIM + c0);
        float p0 = __expf(e0 - m), p1 = __expf(e1 - m);
        float p2 = __expf(e2 - m), p3 = __expf(e3 - m);
        s += p0 + p1 + p2 + p3;
        ACC8(v0, p0)
        ACC8(v1, p1)
        ACC8(v2, p2)
        ACC8(v3, p3)
    }
    for (; j < jeF; j++) {                            // only if je clipped by ECAP
        int s0 = Sls[j];
        float e0 = Els[j * NH + head];
        uint4 v0 = *(const uint4*)(Hu + (size_t)s0 * KDIM + c0);
        float p0 = __expf(e0 - m);
        s += p0;
        ACC8(v0, p0)
    }
    if (je > ECAP) {                                  // never in practice
        float edv = ED[node * NH + head];
        for (int jj = ECAP; jj < je; jj++) {
            int sj = csr_src[beg0 + jj];
            if (sj < 0) continue;
            float e = ES[sj * NH + head] + edv;
            e = (e > 0.f) ? e : 0.2f * e;
            float p = __expf(e - m);
            s += p;
            uint4 v = *(const uint4*)(Hu + (size_t)sj * KDIM + c0);
            ACC8(v, p)
        }
    }
#undef ACC8

    float inv = 1.f / s;
    float4 b0 = *(const float4*)&bias[c0];
    float4 b1 = *(const float4*)&bias[c0 + 4];
    float o[8];
    o[0] = fmaf(a[0], inv, b0.x); o[1] = fmaf(a[1], inv, b0.y);
    o[2] = fmaf(a[2], inv, b0.z); o[3] = fmaf(a[3], inv, b0.w);
    o[4] = fmaf(a[4], inv, b1.x); o[5] = fmaf(a[5], inv, b1.y);
    o[6] = fmaf(a[6], inv, b1.z); o[7] = fmaf(a[7], inv, b1.w);
    if (POOL) {
        int gr = batch[node];
        unsigned* base = outw + (size_t)gr * KDIM + c0;
#pragma unroll
        for (int i = 0; i < 8; i++) {
            int bi = __float_as_int(o[i]);
            unsigned enc = (bi >= 0) ? ((unsigned)bi | 0x80000000u) : ~(unsigned)bi;
            atomicMax(&base[i], enc);
        }
    } else {
        __hip_bfloat16 rb[8];
#pragma unroll
        for (int i = 0; i < 8; i++) {
            float v = RELU ? fmaxf(o[i], 0.f) : o[i];
            rb[i] = __float2bfloat16(v);
        }
        *(uint4*)&Out[(size_t)node * KDIM + c0] = *(uint4*)rb;
    }
}

// ---------------------------------------------------------------------------
// Decode monotone-uint max-pool accumulator back to float (in place).
// ---------------------------------------------------------------------------
__global__ __launch_bounds__(256) void decode_k(unsigned* __restrict__ w, int n) {
    int i = blockIdx.x * 256 + threadIdx.x;
    if (i >= n) return;
    unsigned u = w[i];
    unsigned b = (u & 0x80000000u) ? (u & 0x7fffffffu) : ~u;
    if (u == 0u) b = 0xFF800000u;                    // untouched -> -inf
    w[i] = b;
}

// ---------------------------------------------------------------------------
extern "C" void kernel_launch(void* const* d_in, const int* in_sizes, int n_in,
                              void* d_out, int out_size, void* d_ws, size_t ws_size,
                              hipStream_t stream) {
    const float* x     = (const float*)d_in[0];
    const int*   ei    = (const int*)d_in[1];
    const int*   batch = (const int*)d_in[2];
    const float* W1  = (const float*)d_in[3];
    const float* as1 = (const float*)d_in[4];
    const float* ad1 = (const float*)d_in[5];
    const float* b1  = (const float*)d_in[6];
    const float* W2  = (const float*)d_in[7];
    const float* as2 = (const float*)d_in[8];
    const float* ad2 = (const float*)d_in[9];
    const float* b2  = (const float*)d_in[10];
    const float* W3  = (const float*)d_in[11];
    const float* as3 = (const float*)d_in[12];
    const float* ad3 = (const float*)d_in[13];
    const float* b3  = (const float*)d_in[14];
    unsigned* outw = (unsigned*)d_out;

    // Workspace layout (~130 MB)
    char* p = (char*)d_ws;
    auto alloc = [&](size_t bytes) { char* r = p; p += (bytes + 255) & ~(size_t)255; return r; };
    __hip_bfloat16* Xb  = (__hip_bfloat16*)alloc((size_t)N_NODES_C * 64 * 2);
    __hip_bfloat16* Hb  = (__hip_bfloat16*)alloc((size_t)N_NODES_C * KDIM * 2);
    __hip_bfloat16* Nb  = (__hip_bfloat16*)alloc((size_t)N_NODES_C * KDIM * 2);
    __hip_bfloat16* Wt1 = (__hip_bfloat16*)alloc(256 * 64 * 2);
    __hip_bfloat16* Wt2 = (__hip_bfloat16*)alloc(256 * 256 * 2);
    __hip_bfloat16* Wt3 = (__hip_bfloat16*)alloc(256 * 256 * 2);
    float* ES     = (float*)alloc((size_t)N_NODES_C * 4 * 4);
    float* ED     = (float*)alloc((size_t)N_NODES_C * 4 * 4);
    int* degcur   = (int*)alloc((size_t)(2 * N_NODES_C + 1) * 4);   // deg + cursor, one memset
    int* deg      = degcur;
    int* cursor   = degcur + (N_NODES_C + 1);
    int* rowoff   = (int*)alloc((N_NODES_C + 1) * 4);
    int* csr      = (int*)alloc((size_t)E_PAD * 4 + 256);   // +pad
    int* csrd     = (int*)alloc((size_t)E_PAD * 4);
    int* partials = (int*)alloc(512 * 4);

    // --- zero deg+cursor and d_out (encoded -inf sentinel) ---
    hipMemsetAsync(degcur, 0, (size_t)(2 * N_NODES_C + 1) * 4, stream);
    hipMemsetAsync(outw, 0, (size_t)out_size * 4, stream);
    int ctot = XE + W1E + 2 * WBE;
    conv_all_count<<<(ctot + 255) / 256, 256, 0, stream>>>(
        x, W1, W2, W3, ei, Xb, Wt1, Wt2, Wt3, deg);

    // --- CSR offsets (padded) + scatter(+pad fill) ---
    int nb = (N_NODES_C + 1 + 255) / 256;           // 391
    scan_chunk<<<nb, 256, 0, stream>>>(deg, rowoff, partials, N_NODES_C + 1);
    scan_fix<<<nb, 256, 0, stream>>>(rowoff, partials, N_NODES_C + 1);
    int egrid = (E_TOT + 255) / 256;
    scatter_k<<<egrid, 256, 0, stream>>>(ei, rowoff, cursor, csr, csrd, deg);

    int ggrid = (N_NODES_C + 127) / 128;             // 782 (512-thread blocks)
    int agrid = N_NODES_C / 8;                       // 12500 (exact)
    // --- layer 1: 58(->64) -> 4x64, relu ---
    gemm_mfma<64, 4><<<ggrid, 512, 0, stream>>>(Xb, Wt1, as1, ad1, Hb, ES, ED);
    agg_kernel<4, true, false><<<agrid, 256, 0, stream>>>(Hb, rowoff, csr, csrd, ES, ED, b1, Nb, batch, outw);
    // --- layer 2: 256 -> 4x64, relu ---
    gemm_mfma<256, 4><<<ggrid, 512, 0, stream>>>(Nb, Wt2, as2, ad2, Hb, ES, ED);
    agg_kernel<4, true, false><<<agrid, 256, 0, stream>>>(Hb, rowoff, csr, csrd, ES, ED, b2, Nb, batch, outw);
    // --- layer 3: 256 -> 1x256, no relu; fused max-pool via atomicMax ---
    gemm_mfma<256, 1><<<ggrid, 512, 0, stream>>>(Nb, Wt3, as3, ad3, Hb, ES, ED);
    agg_kernel<1, false, true><<<agrid, 256, 0, stream>>>(Hb, rowoff, csr, csrd, ES, ED, b3, Nb, batch, outw);
    // --- decode pooled maxima to float ---
    decode_k<<<(out_size + 255) / 256, 256, 0, stream>>>(outw, out_size);
}

// Round 16
// 314.721 us; speedup vs baseline: 2.7467x; 2.7467x over previous
//
#include <hip/hip_runtime.h>
#include <hip/hip_bf16.h>
#include <math.h>

// Problem constants (from reference)
#define N_NODES_C 100000
#define E_ORIG    400000
#define E_TOT     500000   // + self loops
#define E_PAD     (E_TOT + 3 * N_NODES_C)   // CSR padded to multiple-of-4 per node
#define N_GRAPHS_C 2000
#define KDIM      256      // HEADS*HID = OUT

typedef __attribute__((ext_vector_type(8))) short short8v;  // 8 bf16 = 4 VGPR
typedef __attribute__((ext_vector_type(4))) float f32x4;

__device__ __forceinline__ void gload_lds16(const void* g, void* l) {
    __builtin_amdgcn_global_load_lds(
        (const __attribute__((address_space(1))) unsigned int*)g,
        (__attribute__((address_space(3))) unsigned int*)l, 16, 0, 0);
}

__device__ __forceinline__ float bflo(unsigned u) { return __uint_as_float(u << 16); }
__device__ __forceinline__ float bfhi(unsigned u) { return __uint_as_float(u & 0xffff0000u); }

// ---------------------------------------------------------------------------
// Conversions to bf16 + degree count, ONE kernel (regions by flat index).
// ---------------------------------------------------------------------------
#define XE  (N_NODES_C * 64)
#define W1E (256 * 64)
#define WBE (256 * 256)
__global__ __launch_bounds__(256) void conv_all_count(
        const float* __restrict__ x, const float* __restrict__ W1,
        const float* __restrict__ W2, const float* __restrict__ W3,
        const int* __restrict__ ei,
        __hip_bfloat16* __restrict__ Xb, __hip_bfloat16* __restrict__ Wt1,
        __hip_bfloat16* __restrict__ Wt2, __hip_bfloat16* __restrict__ Wt3,
        int* __restrict__ deg) {
    int idx = blockIdx.x * 256 + threadIdx.x;
    if (idx < E_TOT) {
        int d = (idx < E_ORIG) ? ei[E_ORIG + idx] : (idx - E_ORIG);
        atomicAdd(&deg[d], 1);
    }
    if (idx < XE) {
        int row = idx >> 6, c = idx & 63;
        float v = (c < 58) ? x[row * 58 + c] : 0.f;
        Xb[idx] = __float2bfloat16(v);
    } else if (idx < XE + W1E) {
        int i = idx - XE;
        int c = i >> 6, k = i & 63;               // KPAD=64, K=58
        float v = (k < 58) ? W1[k * 256 + c] : 0.f;
        Wt1[i] = __float2bfloat16(v);
    } else if (idx < XE + W1E + WBE) {
        int i = idx - XE - W1E;
        int c = i >> 8, k = i & 255;
        Wt2[i] = __float2bfloat16(W2[k * 256 + c]);
    } else if (idx < XE + W1E + 2 * WBE) {
        int i = idx - XE - W1E - WBE;
        int c = i >> 8, k = i & 255;
        Wt3[i] = __float2bfloat16(W3[k * 256 + c]);
    }
}

// ---------------------------------------------------------------------------
// CSR scan over PADDED degrees ((deg+3)&~3) + fix-up + scatter (+pad fill).
// ---------------------------------------------------------------------------
__global__ void scan_chunk(const int* __restrict__ in, int* __restrict__ out,
                           int* __restrict__ partials, int n) {
    __shared__ int s[256];
    int tid = threadIdx.x;
    int i = blockIdx.x * 256 + tid;
    int dv = (i < n) ? in[i] : 0;
    int v = (dv + 3) & ~3;                     // padded degree (0 stays 0)
    s[tid] = v;
    __syncthreads();
    for (int off = 1; off < 256; off <<= 1) {
        int t = (tid >= off) ? s[tid - off] : 0;
        __syncthreads();
        s[tid] += t;
        __syncthreads();
    }
    if (i < n) out[i] = s[tid] - v;            // exclusive within chunk
    if (tid == 255) partials[blockIdx.x] = s[255];
}

__global__ void scan_fix(int* __restrict__ rowoff, const int* __restrict__ partials, int n) {
    __shared__ int sred[256];
    int t = threadIdx.x;
    int acc = 0;
    for (int i = t; i < blockIdx.x; i += 256) acc += partials[i];
    sred[t] = acc;
    __syncthreads();
    for (int off = 128; off; off >>= 1) {
        if (t < off) sred[t] += sred[t + off];
        __syncthreads();
    }
    int base = sred[0];
    int i = blockIdx.x * 256 + t;
    if (i < n) rowoff[i] += base;
}

// scatter + pad fill fused: pads write disjoint slots [base+deg, base+paddeg)
__global__ void scatter_k(const int* __restrict__ ei, const int* __restrict__ rowoff,
                          int* cursor, int* __restrict__ csr_src,
                          int* __restrict__ csr_dst, const int* __restrict__ deg) {
    int e = blockIdx.x * 256 + threadIdx.x;
    if (e < E_TOT) {
        int s, d;
        if (e < E_ORIG) { s = ei[e]; d = ei[E_ORIG + e]; }
        else            { s = e - E_ORIG; d = s; }
        int pos = rowoff[d] + atomicAdd(&cursor[d], 1);
        csr_src[pos] = s;
        csr_dst[pos] = d;
    }
    if (e < N_NODES_C) {
        int dg = deg[e];
        int pd = (dg + 3) & ~3;
        int base = rowoff[e];
        for (int j = dg; j < pd; j++) {
            csr_src[base + j] = e | 0x80000000;
            csr_dst[base + j] = e;
        }
    }
}

// ---------------------------------------------------------------------------
// MFMA bf16 GEMM: H = X @ W + fused attention dots ES/ED.
// 128 rows x 256 cols tile, 8 waves (512 threads), wave tile 32x128,
// acc[2][8] = 64 AGPR; __launch_bounds__(512,4) caps 128 unified regs ->
// 4 waves/SIMD, 2 blocks/CU (50% occ). Staging identical to r14.
// ---------------------------------------------------------------------------
template <int KPAD, int NH>
__global__ __launch_bounds__(512, 4) void gemm_mfma(
        const __hip_bfloat16* __restrict__ Xb, const __hip_bfloat16* __restrict__ Wt,
        const float* __restrict__ ASRC, const float* __restrict__ ADST,
        __hip_bfloat16* __restrict__ H, float* __restrict__ ES, float* __restrict__ ED) {
    __shared__ char As[128 * 128];                   // [128 rows][64 k] bf16
    __shared__ char Bs[256 * 128];                   // [256 cols][64 k] bf16
    __shared__ float red[2][128][2];                 // NH==1 cross-wave ES/ED

    const int t = threadIdx.x;
    const int wv = t >> 6, lane = t & 63;
    const int wr = wv >> 1, wc = wv & 1;             // wr 0..3 (32 rows), wc 0..1
    const int r15 = lane & 15, hi = lane >> 4;
    const int n0 = blockIdx.x * 128;
    const int srow = lane >> 3;                      // staging: row-within-8
    const int sx = ((lane & 7) ^ srow) * 16;         // pre-swizzled source chunk
    constexpr int KB = KPAD * 2;                     // row bytes

    f32x4 acc[2][8];
#pragma unroll
    for (int m = 0; m < 2; m++)
#pragma unroll
        for (int n = 0; n < 8; n++) acc[m][n] = (f32x4){0.f, 0.f, 0.f, 0.f};

    for (int kt = 0; kt < KPAD / 64; kt++) {
        if (kt) __syncthreads();
        const int k0b = kt * 128;
#pragma unroll
        for (int p = 0; p < 2; p++) {                // A: 16 segs, 2/wave
            int i = wv * 2 + p;
            int gr = n0 + i * 8 + srow;
            if (gr > N_NODES_C - 1) gr = N_NODES_C - 1;
            gload_lds16((const char*)Xb + (size_t)gr * KB + k0b + sx, As + i * 1024);
        }
#pragma unroll
        for (int p = 0; p < 4; p++) {                // B: 32 segs, 4/wave
            int i = wv * 4 + p;
            int col = i * 8 + srow;
            gload_lds16((const char*)Wt + (size_t)col * KB + k0b + sx, Bs + i * 1024);
        }
        asm volatile("s_waitcnt vmcnt(0)" ::: "memory");
        __syncthreads();

#pragma unroll
        for (int ks = 0; ks < 2; ks++) {
            const int cx = ((ks * 4 + hi) ^ (r15 & 7)) * 16;  // swizzled chunk byte
            short8v a0 = *(const short8v*)(As + (wr * 32 + 0  + r15) * 128 + cx);
            short8v a1 = *(const short8v*)(As + (wr * 32 + 16 + r15) * 128 + cx);
#pragma unroll
            for (int n = 0; n < 8; n++) {
                short8v b = *(const short8v*)(Bs + (wc * 128 + n * 16 + r15) * 128 + cx);
                acc[0][n] = __builtin_amdgcn_mfma_f32_16x16x32_bf16(a0, b, acc[0][n], 0, 0, 0);
                acc[1][n] = __builtin_amdgcn_mfma_f32_16x16x32_bf16(a1, b, acc[1][n], 0, 0, 0);
            }
        }
    }

    // ---- epilogue: H (bf16) + attention dots ----
    float asv[8], adv[8];
#pragma unroll
    for (int n = 0; n < 8; n++) {
        int col = wc * 128 + n * 16 + r15;
        asv[n] = ASRC[col];
        adv[n] = ADST[col];
    }

#pragma unroll
    for (int m = 0; m < 2; m++) {
#pragma unroll
        for (int j = 0; j < 4; j++) {
            int lrow = wr * 32 + m * 16 + hi * 4 + j;
            int row = n0 + lrow;
            bool ok = row < N_NODES_C;
            if (ok) {
#pragma unroll
                for (int n = 0; n < 8; n++)
                    H[(size_t)row * KDIM + wc * 128 + n * 16 + r15] =
                        __float2bfloat16(acc[m][n][j]);
            }
            if (NH == 4) {
                float p0s = 0.f, p1s = 0.f, p0d = 0.f, p1d = 0.f;
#pragma unroll
                for (int n = 0; n < 4; n++) {
                    p0s = fmaf(acc[m][n][j], asv[n], p0s);
                    p0d = fmaf(acc[m][n][j], adv[n], p0d);
                    p1s = fmaf(acc[m][n + 4][j], asv[n + 4], p1s);
                    p1d = fmaf(acc[m][n + 4][j], adv[n + 4], p1d);
                }
#pragma unroll
                for (int s = 8; s; s >>= 1) {
                    p0s += __shfl_xor(p0s, s, 16);
                    p0d += __shfl_xor(p0d, s, 16);
                    p1s += __shfl_xor(p1s, s, 16);
                    p1d += __shfl_xor(p1d, s, 16);
                }
                if (r15 == 0 && ok) {
                    ES[row * 4 + wc * 2 + 0] = p0s;
                    ES[row * 4 + wc * 2 + 1] = p1s;
                    ED[row * 4 + wc * 2 + 0] = p0d;
                    ED[row * 4 + wc * 2 + 1] = p1d;
                }
            } else {
                float ps = 0.f, pd = 0.f;
#pragma unroll
                for (int n = 0; n < 8; n++) {
                    ps = fmaf(acc[m][n][j], asv[n], ps);
                    pd = fmaf(acc[m][n][j], adv[n], pd);
                }
#pragma unroll
                for (int s = 8; s; s >>= 1) {
                    ps += __shfl_xor(ps, s, 16);
                    pd += __shfl_xor(pd, s, 16);
                }
                if (r15 == 0) { red[0][lrow][wc] = ps; red[1][lrow][wc] = pd; }
            }
        }
    }
    if (NH == 1) {
        __syncthreads();
        if (t < 128) {
            int row = n0 + t;
            if (row < N_NODES_C) {
                ES[row] = red[0][t][0] + red[0][t][1];
                ED[row] = red[1][t][0] + red[1][t][1];
            }
        }
    }
}

// ---------------------------------------------------------------------------
// Fused per-dst softmax aggregation (r14 version — plain bf16 stores; the
// r15 atomicMax-pool fusion regressed 12x: device-scope atomics bypass L2
// on gfx950 due to XCD non-coherence -> HBM RMW per atomic).
// ---------------------------------------------------------------------------
#define ECAP 160
template <int NH, bool RELU>
__global__ __launch_bounds__(256) void agg_kernel(
        const __hip_bfloat16* __restrict__ H, const int* __restrict__ rowoff,
        const int* __restrict__ csr_src, const int* __restrict__ csr_dst,
        const float* __restrict__ ES, const float* __restrict__ ED,
        const float* __restrict__ bias, __hip_bfloat16* __restrict__ Out) {
    __shared__ float Els[ECAP * NH];
    __shared__ int   Sls[ECAP];
    __shared__ int   roff[9];
    int t = threadIdx.x;
    int n0 = blockIdx.x * 8;                          // grid*8 == N exactly
    if (t < 9) roff[t] = rowoff[n0 + t];
    __syncthreads();
    int beg0 = roff[0];
    int ne = roff[8] - beg0;
    int nl = (ne < ECAP) ? ne : ECAP;
    for (int j = t; j < nl; j += 256) {
        int slot = beg0 + j;
        int srcj = csr_src[slot];
        bool padj = srcj < 0;
        srcj &= 0x7fffffff;
        int dj = csr_dst[slot];
        Sls[j] = srcj;
        if (NH == 4) {
            float4 es = *(const float4*)&ES[srcj * 4];
            float4 ed = *(const float4*)&ED[dj * 4];
            float e;
            e = es.x + ed.x; e = (e > 0.f) ? e : 0.2f * e; Els[j * 4 + 0] = padj ? -1e30f : e;
            e = es.y + ed.y; e = (e > 0.f) ? e : 0.2f * e; Els[j * 4 + 1] = padj ? -1e30f : e;
            e = es.z + ed.z; e = (e > 0.f) ? e : 0.2f * e; Els[j * 4 + 2] = padj ? -1e30f : e;
            e = es.w + ed.w; e = (e > 0.f) ? e : 0.2f * e; Els[j * 4 + 3] = padj ? -1e30f : e;
        } else {
            float e = ES[srcj] + ED[dj];
            e = (e > 0.f) ? e : 0.2f * e;
            Els[j] = padj ? -1e30f : e;
        }
    }
    __syncthreads();

    int g = t >> 5;
    int node = n0 + g;
    int l = t & 31;
    int c0 = l * 8;
    int head = (NH == 4) ? (l >> 3) : 0;
    int jb = roff[g] - beg0, je = roff[g + 1] - beg0;
    int jeF = (je < ECAP) ? je : ECAP;

    float m = -1e30f;
    for (int j = jb; j < jeF; j++) m = fmaxf(m, Els[j * NH + head]);
    if (je > ECAP) {                                  // never in practice
        float edv = ED[node * NH + head];
        for (int j = ECAP; j < je; j++) {
            int sj = csr_src[beg0 + j];
            if (sj < 0) continue;
            float e = ES[sj * NH + head] + edv;
            e = (e > 0.f) ? e : 0.2f * e;
            m = fmaxf(m, e);
        }
    }

    float s = 0.f;
    float a[8];
#pragma unroll
    for (int i = 0; i < 8; i++) a[i] = 0.f;
    const unsigned short* Hu = (const unsigned short*)H;

#define ACC8(v, p) \
    a[0] = fmaf(p, bflo(v.x), a[0]); a[1] = fmaf(p, bfhi(v.x), a[1]); \
    a[2] = fmaf(p, bflo(v.y), a[2]); a[3] = fmaf(p, bfhi(v.y), a[3]); \
    a[4] = fmaf(p, bflo(v.z), a[4]); a[5] = fmaf(p, bfhi(v.z), a[5]); \
    a[6] = fmaf(p, bflo(v.w), a[6]); a[7] = fmaf(p, bfhi(v.w), a[7]);

    int j = jb;
    for (; j + 4 <= jeF; j += 4) {                    // pure quads (padded CSR)
        int s0 = Sls[j], s1 = Sls[j + 1], s2 = Sls[j + 2], s3 = Sls[j + 3];
        float e0 = Els[(j + 0) * NH + head], e1 = Els[(j + 1) * NH + head];
        float e2 = Els[(j + 2) * NH + head], e3 = Els[(j + 3) * NH + head];
        uint4 v0 = *(const uint4*)(Hu + (size_t)s0 * KDIM + c0);
        uint4 v1 = *(const uint4*)(Hu + (size_t)s1 * KDIM + c0);
        uint4 v2 = *(const uint4*)(Hu + (size_t)s2 * KDIM + c0);
        uint4 v3 = *(const uint4*)(Hu + (size_t)s3 * KDIM + c0);
        float p0 = __expf(e0 - m), p1 = __expf(e1 - m);
        float p2 = __expf(e2 - m), p3 = __expf(e3 - m);
        s += p0 + p1 + p2 + p3;
        ACC8(v0, p0)
        ACC8(v1, p1)
        ACC8(v2, p2)
        ACC8(v3, p3)
    }
    for (; j < jeF; j++) {                            // only if je clipped by ECAP
        int s0 = Sls[j];
        float e0 = Els[j * NH + head];
        uint4 v0 = *(const uint4*)(Hu + (size_t)s0 * KDIM + c0);
        float p0 = __expf(e0 - m);
        s += p0;
        ACC8(v0, p0)
    }
    if (je > ECAP) {                                  // never in practice
        float edv = ED[node * NH + head];
        for (int jj = ECAP; jj < je; jj++) {
            int sj = csr_src[beg0 + jj];
            if (sj < 0) continue;
            float e = ES[sj * NH + head] + edv;
            e = (e > 0.f) ? e : 0.2f * e;
            float p = __expf(e - m);
            s += p;
            uint4 v = *(const uint4*)(Hu + (size_t)sj * KDIM + c0);
            ACC8(v, p)
        }
    }
#undef ACC8

    float inv = 1.f / s;
    float4 b0 = *(const float4*)&bias[c0];
    float4 b1 = *(const float4*)&bias[c0 + 4];
    float o[8];
    o[0] = fmaf(a[0], inv, b0.x); o[1] = fmaf(a[1], inv, b0.y);
    o[2] = fmaf(a[2], inv, b0.z); o[3] = fmaf(a[3], inv, b0.w);
    o[4] = fmaf(a[4], inv, b1.x); o[5] = fmaf(a[5], inv, b1.y);
    o[6] = fmaf(a[6], inv, b1.z); o[7] = fmaf(a[7], inv, b1.w);
    __hip_bfloat16 rb[8];
#pragma unroll
    for (int i = 0; i < 8; i++) {
        float v = RELU ? fmaxf(o[i], 0.f) : o[i];
        rb[i] = __float2bfloat16(v);
    }
    *(uint4*)&Out[(size_t)node * KDIM + c0] = *(uint4*)rb;
}

// ---------------------------------------------------------------------------
// Global max pool over graphs (r14 version).
// ---------------------------------------------------------------------------
__global__ __launch_bounds__(256) void pool_k(
        const __hip_bfloat16* __restrict__ O, const int* __restrict__ batch,
        float* __restrict__ out) {
    __shared__ int range[2];
    __shared__ float red[3][256];
    int g = blockIdx.x, k = threadIdx.x;
    if (k < 2) {
        int v = g + k;
        int lo = 0, hi = N_NODES_C;
        while (lo < hi) { int mid = (lo + hi) >> 1; if (batch[mid] < v) lo = mid + 1; else hi = mid; }
        range[k] = lo;
    }
    __syncthreads();
    int cg = k & 63;
    int ro = k >> 6;
    float m0 = -INFINITY, m1 = -INFINITY, m2 = -INFINITY, m3 = -INFINITY;
    const unsigned short* Ou = (const unsigned short*)O;
    for (int i = range[0] + ro; i < range[1]; i += 4) {
        uint2 v = *(const uint2*)(Ou + (size_t)i * KDIM + cg * 4);
        m0 = fmaxf(m0, bflo(v.x)); m1 = fmaxf(m1, bfhi(v.x));
        m2 = fmaxf(m2, bflo(v.y)); m3 = fmaxf(m3, bfhi(v.y));
    }
    if (ro) {
        red[ro - 1][cg * 4 + 0] = m0; red[ro - 1][cg * 4 + 1] = m1;
        red[ro - 1][cg * 4 + 2] = m2; red[ro - 1][cg * 4 + 3] = m3;
    }
    __syncthreads();
    if (ro == 0) {
        m0 = fmaxf(fmaxf(m0, red[0][cg * 4 + 0]), fmaxf(red[1][cg * 4 + 0], red[2][cg * 4 + 0]));
        m1 = fmaxf(fmaxf(m1, red[0][cg * 4 + 1]), fmaxf(red[1][cg * 4 + 1], red[2][cg * 4 + 1]));
        m2 = fmaxf(fmaxf(m2, red[0][cg * 4 + 2]), fmaxf(red[1][cg * 4 + 2], red[2][cg * 4 + 2]));
        m3 = fmaxf(fmaxf(m3, red[0][cg * 4 + 3]), fmaxf(red[1][cg * 4 + 3], red[2][cg * 4 + 3]));
        float4 o = make_float4(m0, m1, m2, m3);
        *(float4*)&out[(size_t)g * KDIM + cg * 4] = o;
    }
}

// ---------------------------------------------------------------------------
extern "C" void kernel_launch(void* const* d_in, const int* in_sizes, int n_in,
                              void* d_out, int out_size, void* d_ws, size_t ws_size,
                              hipStream_t stream) {
    const float* x     = (const float*)d_in[0];
    const int*   ei    = (const int*)d_in[1];
    const int*   batch = (const int*)d_in[2];
    const float* W1  = (const float*)d_in[3];
    const float* as1 = (const float*)d_in[4];
    const float* ad1 = (const float*)d_in[5];
    const float* b1  = (const float*)d_in[6];
    const float* W2  = (const float*)d_in[7];
    const float* as2 = (const float*)d_in[8];
    const float* ad2 = (const float*)d_in[9];
    const float* b2  = (const float*)d_in[10];
    const float* W3  = (const float*)d_in[11];
    const float* as3 = (const float*)d_in[12];
    const float* ad3 = (const float*)d_in[13];
    const float* b3  = (const float*)d_in[14];
    float* out = (float*)d_out;

    // Workspace layout (~130 MB)
    char* p = (char*)d_ws;
    auto alloc = [&](size_t bytes) { char* r = p; p += (bytes + 255) & ~(size_t)255; return r; };
    __hip_bfloat16* Xb  = (__hip_bfloat16*)alloc((size_t)N_NODES_C * 64 * 2);
    __hip_bfloat16* Hb  = (__hip_bfloat16*)alloc((size_t)N_NODES_C * KDIM * 2);
    __hip_bfloat16* Nb  = (__hip_bfloat16*)alloc((size_t)N_NODES_C * KDIM * 2);
    __hip_bfloat16* Wt1 = (__hip_bfloat16*)alloc(256 * 64 * 2);
    __hip_bfloat16* Wt2 = (__hip_bfloat16*)alloc(256 * 256 * 2);
    __hip_bfloat16* Wt3 = (__hip_bfloat16*)alloc(256 * 256 * 2);
    float* ES     = (float*)alloc((size_t)N_NODES_C * 4 * 4);
    float* ED     = (float*)alloc((size_t)N_NODES_C * 4 * 4);
    int* degcur   = (int*)alloc((size_t)(2 * N_NODES_C + 1) * 4);   // deg + cursor, one memset
    int* deg      = degcur;
    int* cursor   = degcur + (N_NODES_C + 1);
    int* rowoff   = (int*)alloc((N_NODES_C + 1) * 4);
    int* csr      = (int*)alloc((size_t)E_PAD * 4 + 256);   // +pad
    int* csrd     = (int*)alloc((size_t)E_PAD * 4);
    int* partials = (int*)alloc(512 * 4);

    // --- zero deg+cursor, then conversions + degree count in one kernel ---
    hipMemsetAsync(degcur, 0, (size_t)(2 * N_NODES_C + 1) * 4, stream);
    int ctot = XE + W1E + 2 * WBE;
    conv_all_count<<<(ctot + 255) / 256, 256, 0, stream>>>(
        x, W1, W2, W3, ei, Xb, Wt1, Wt2, Wt3, deg);

    // --- CSR offsets (padded) + scatter(+pad fill) ---
    int nb = (N_NODES_C + 1 + 255) / 256;           // 391
    scan_chunk<<<nb, 256, 0, stream>>>(deg, rowoff, partials, N_NODES_C + 1);
    scan_fix<<<nb, 256, 0, stream>>>(rowoff, partials, N_NODES_C + 1);
    int egrid = (E_TOT + 255) / 256;
    scatter_k<<<egrid, 256, 0, stream>>>(ei, rowoff, cursor, csr, csrd, deg);

    int ggrid = (N_NODES_C + 127) / 128;             // 782 (512-thread blocks)
    int agrid = N_NODES_C / 8;                       // 12500 (exact)
    // --- layer 1: 58(->64) -> 4x64, relu ---
    gemm_mfma<64, 4><<<ggrid, 512, 0, stream>>>(Xb, Wt1, as1, ad1, Hb, ES, ED);
    agg_kernel<4, true><<<agrid, 256, 0, stream>>>(Hb, rowoff, csr, csrd, ES, ED, b1, Nb);
    // --- layer 2: 256 -> 4x64, relu ---
    gemm_mfma<256, 4><<<ggrid, 512, 0, stream>>>(Nb, Wt2, as2, ad2, Hb, ES, ED);
    agg_kernel<4, true><<<agrid, 256, 0, stream>>>(Hb, rowoff, csr, csrd, ES, ED, b2, Nb);
    // --- layer 3: 256 -> 1x256, no relu ---
    gemm_mfma<256, 1><<<ggrid, 512, 0, stream>>>(Nb, Wt3, as3, ad3, Hb, ES, ED);
    agg_kernel<1, false><<<agrid, 256, 0, stream>>>(Hb, rowoff, csr, csrd, ES, ED, b3, Nb);
    // --- global max pool ---
    pool_k<<<N_GRAPHS_C, 256, 0, stream>>>(Nb, batch, out);
}